// Round 5
// baseline (724.284 us; speedup 1.0000x reference)
//
#include <hip/hip_runtime.h>
#include <math.h>

// MultiHeadSelfAttention: B=4, S=2048, E=1024, H=16, Dh=64. fp32 in/out,
// bf16 MFMA internally, fp32 accumulate.
//
// Stage 0: cvt_x    -> x fp32 -> bf16 Xb (aliased w/ attn-out ws slot)
// Stage 1: qkv_gemm -> ws (bf16): q (pre-scaled 1/32) [bh][s][d],
//                     k [bh][s][d], v TRANSPOSED [bh][d][s]
//                     (A-tile via async global_load_lds, B fp32->bf16 VALU)
// Stage 2: attn     -> ZERO-barrier flash attention (S^T = K Q^T, per-lane
//                      softmax, __expf), K/V^T frags direct from global,
//                      P per-wave in LDS. 4 blocks/CU fully resident.
// Stage 3: out_gemm -> @ Wo^T + bo -> d_out (fp32)

typedef __bf16 bf16;
typedef __attribute__((ext_vector_type(8))) short short8;
typedef __attribute__((ext_vector_type(4))) short s4v;
typedef __attribute__((ext_vector_type(4))) float floatx4;

#define MFMA16(a, b, c) __builtin_amdgcn_mfma_f32_16x16x32_bf16((a), (b), (c), 0, 0, 0)

#define BS_STRIDE 56    // B tile rows: 32 -> 56 shorts (112 B)
#define PQ_STRIDE 136   // P rows: 128 -> 136 shorts (272 B, 16B-aligned)

#define SCALE32 0.03125f   // 1/sqrt(1024); folded into q at stage 1

// fp32 x8 -> bf16 x8 (short8 bit pattern)
__device__ __forceinline__ short8 frag8f(const float* __restrict__ p) {
    const floatx4 a = *(const floatx4*)p;
    const floatx4 b = *(const floatx4*)(p + 4);
    short8 r;
#pragma unroll
    for (int j = 0; j < 4; j++) {
        r[j]     = __builtin_bit_cast(short, (bf16)a[j]);
        r[4 + j] = __builtin_bit_cast(short, (bf16)b[j]);
    }
    return r;
}

// async 16B/lane global->LDS (wave-uniform LDS base + lane*16)
__device__ __forceinline__ void gll16(const bf16* gp, short* lp) {
    __builtin_amdgcn_global_load_lds(
        (const __attribute__((address_space(1))) void*)gp,
        (__attribute__((address_space(3))) void*)lp, 16, 0, 0);
}

// ---------------------------------------------------------------------------
// Stage 0: x fp32 -> bf16. grid 8192 x 256 covers 8,388,608 elems exactly.
// ---------------------------------------------------------------------------
__global__ __launch_bounds__(256) void cvt_x(
    const float* __restrict__ x, bf16* __restrict__ xb)
{
    const size_t i = ((size_t)blockIdx.x * 256 + threadIdx.x) * 4;
    const floatx4 v = *(const floatx4*)(x + i);
    s4v p;
#pragma unroll
    for (int j = 0; j < 4; j++) p[j] = __builtin_bit_cast(short, (bf16)v[j]);
    *(s4v*)(xb + i) = p;
}

// ---------------------------------------------------------------------------
// 128x128 GEMM core: C[m][n] = sum_k A[m][k]*B[n][k]. A bf16 (async staged,
// unpadded 128x32 LDS), B fp32 (VALU-converted, padded). BK=32.
// ---------------------------------------------------------------------------
__device__ __forceinline__ void gemm128_async(
    const bf16* __restrict__ A, const float* __restrict__ B, int K,
    int m0, int n0, short* As, short* Bs, floatx4 acc[4][4])
{
    const int tid  = threadIdx.x;
    const int lane = tid & 63;
    const int w    = tid >> 6;
    const int wm   = w >> 1, wn = w & 1;
    const int g    = lane >> 4, c = lane & 15;
    const int lrow = tid >> 2;
    const int lc8  = (tid & 3) * 8;
    const int arow = (lane >> 2);        // 0..15 within chunk
    const int acol = (lane & 3) * 8;     // 0,8,16,24

#pragma unroll
    for (int mi = 0; mi < 4; mi++)
#pragma unroll
        for (int ni = 0; ni < 4; ni++)
            acc[mi][ni] = (floatx4){0.f, 0.f, 0.f, 0.f};

    for (int k0 = 0; k0 < K; k0 += 32) {
        // A: 2 async wave-calls; chunk = j*4+w covers rows chunk*16..+15
#pragma unroll
        for (int j = 0; j < 2; j++) {
            const int chunk = j * 4 + w;
            gll16(A + (size_t)(m0 + chunk * 16 + arow) * K + k0 + acol,
                  As + chunk * 512);
        }
        // B: fp32 -> bf16 VALU staging
        *(short8*)(Bs + lrow * BS_STRIDE + lc8) =
            frag8f(B + (size_t)(n0 + lrow) * K + k0 + lc8);
        *(short8*)(Bs + (lrow + 64) * BS_STRIDE + lc8) =
            frag8f(B + (size_t)(n0 + lrow + 64) * K + k0 + lc8);
        __syncthreads();

        short8 af[4], bfr[4];
#pragma unroll
        for (int mi = 0; mi < 4; mi++)
            af[mi] = *(const short8*)(As + (wm * 64 + mi * 16 + c) * 32 + g * 8);
#pragma unroll
        for (int ni = 0; ni < 4; ni++)
            bfr[ni] = *(const short8*)(Bs + (wn * 64 + ni * 16 + c) * BS_STRIDE + g * 8);
#pragma unroll
        for (int mi = 0; mi < 4; mi++)
#pragma unroll
            for (int ni = 0; ni < 4; ni++)
                acc[mi][ni] = MFMA16(af[mi], bfr[ni], acc[mi][ni]);
        __syncthreads();
    }
}

// ---------------------------------------------------------------------------
// Stage 1: q/k/v projections from Xb (bf16). q scaled 1/32, [bh][s][64];
//          k [bh][s][64]; v TRANSPOSED [bh][64][2048]. grid (8,64,3).
// ---------------------------------------------------------------------------
__global__ __launch_bounds__(256) void qkv_gemm(
    const bf16* __restrict__ Xb,
    const float* __restrict__ Wq, const float* __restrict__ Wk, const float* __restrict__ Wv,
    const float* __restrict__ bq, const float* __restrict__ bk, const float* __restrict__ bv,
    bf16* __restrict__ qkv)
{
    __shared__ __align__(16) short As[128 * 32];
    __shared__ __align__(16) short Bs[128 * BS_STRIDE];

    const int z = blockIdx.z;
    const float* W    = (z == 0) ? Wq : (z == 1) ? Wk : Wv;
    const float* bias = (z == 0) ? bq : (z == 1) ? bk : bv;
    bf16* outz = qkv + (size_t)z * (8192u * 1024u);
    const float oscale = (z == 0) ? SCALE32 : 1.0f;

    const int m0 = blockIdx.y * 128;
    const int n0 = blockIdx.x * 128;

    floatx4 acc[4][4];
    gemm128_async(Xb, W, 1024, m0, n0, As, Bs, acc);

    const int lane = threadIdx.x & 63;
    const int w = threadIdx.x >> 6;
    const int wm = w >> 1, wn = w & 1;
    const int g = lane >> 4, c = lane & 15;

    if (z < 2) {
#pragma unroll
        for (int ni = 0; ni < 4; ni++) {
            const int n = n0 + wn * 64 + ni * 16 + c;
            const float bb = bias[n];
            const int h = n >> 6, d = n & 63;
#pragma unroll
            for (int mi = 0; mi < 4; mi++) {
#pragma unroll
                for (int r = 0; r < 4; r++) {
                    const int m = m0 + wm * 64 + mi * 16 + g * 4 + r;
                    const int b = m >> 11, s = m & 2047;
                    outz[(((size_t)((b << 4) | h)) * 2048 + s) * 64 + d] =
                        (bf16)((acc[mi][ni][r] + bb) * oscale);
                }
            }
        }
    } else {
        // V transposed: [bh][d][s]; 4 regs = 4 consecutive s -> b64 store
#pragma unroll
        for (int ni = 0; ni < 4; ni++) {
            const int n = n0 + wn * 64 + ni * 16 + c;
            const float bb = bias[n];
            const int h = n >> 6, d = n & 63;
#pragma unroll
            for (int mi = 0; mi < 4; mi++) {
                const int m = m0 + wm * 64 + mi * 16 + g * 4;
                const int b = m >> 11, s = m & 2047;
                s4v pk;
#pragma unroll
                for (int r = 0; r < 4; r++)
                    pk[r] = __builtin_bit_cast(short, (bf16)(acc[mi][ni][r] + bb));
                *(s4v*)(outz + (((size_t)((b << 4) | h)) * 64 + d) * 2048 + s) = pk;
            }
        }
    }
}

// ---------------------------------------------------------------------------
// Stage 2: ZERO-barrier flash attention. grid (16, 64), block 256 (4 waves),
// 4 blocks/CU fully resident. Wave owns 32 queries; 16 K-blocks of 128 keys.
// S^T = K*Q^T  (C-layout: q = lane&15 -> per-lane softmax stats)
// O^T = V^T*P  (V^T frags direct from global [d][s]; P per-wave LDS)
// ---------------------------------------------------------------------------
__global__ __launch_bounds__(256, 4) void attn_kernel(
    const bf16* __restrict__ qkv, bf16* __restrict__ attn_out)
{
    __shared__ __align__(16) short Pq[4 * 32 * PQ_STRIDE];  // 34,816 B

    const int bh = blockIdx.y;            // b = bh>>4, h = bh&15
    const int q0 = blockIdx.x * 128;
    const bf16* Q   = qkv + (size_t)bh * 131072u;                 // [s][64], pre-scaled
    const bf16* Kp  = qkv + 8388608u + (size_t)bh * 131072u;      // [s][64]
    const bf16* Vtg = qkv + 16777216u + (size_t)bh * 131072u;     // [64][2048]

    const int tid  = threadIdx.x;
    const int lane = tid & 63;
    const int w    = tid >> 6;
    const int g    = lane >> 4, c = lane & 15;
    short* Pw = Pq + w * 32 * PQ_STRIDE;

    // Q fragments (B-operand: n = lane&15 = q, k-contiguous), resident
    short8 qf[2][2];
#pragma unroll
    for (int mi = 0; mi < 2; mi++)
#pragma unroll
        for (int ks = 0; ks < 2; ks++)
            qf[mi][ks] = *(const short8*)(Q + (size_t)(q0 + w * 32 + mi * 16 + c) * 64
                                            + ks * 32 + g * 8);

    floatx4 o[2][4];
#pragma unroll
    for (int mi = 0; mi < 2; mi++)
#pragma unroll
        for (int di = 0; di < 4; di++)
            o[mi][di] = (floatx4){0.f, 0.f, 0.f, 0.f};
    float m_run[2] = {-1e30f, -1e30f};
    float l_run[2] = {0.f, 0.f};

    for (int kb = 0; kb < 16; kb++) {
        const int k0 = kb * 128;

#pragma unroll
        for (int mi = 0; mi < 2; mi++) {
            // S^T = K * Q^T : 16 queries x 128 keys
            floatx4 sT[8];
#pragma unroll
            for (int ni = 0; ni < 8; ni++) sT[ni] = (floatx4){0.f, 0.f, 0.f, 0.f};
#pragma unroll
            for (int ks = 0; ks < 2; ks++) {
                short8 kf[8];
#pragma unroll
                for (int ni = 0; ni < 8; ni++)
                    kf[ni] = *(const short8*)(Kp + (size_t)(k0 + ni * 16 + c) * 64
                                                 + ks * 32 + g * 8);
#pragma unroll
                for (int ni = 0; ni < 8; ni++)
                    sT[ni] = MFMA16(kf[ni], qf[mi][ks], sT[ni]);
            }

            // per-lane online softmax (this lane's query = mi*16 + c)
            float mx = -1e30f;
#pragma unroll
            for (int ni = 0; ni < 8; ni++)
#pragma unroll
                for (int r = 0; r < 4; r++) mx = fmaxf(mx, sT[ni][r]);
            mx = fmaxf(mx, __shfl_xor(mx, 16));
            mx = fmaxf(mx, __shfl_xor(mx, 32));
            const float mnew = fmaxf(m_run[mi], mx);
            const float alpha = __expf(m_run[mi] - mnew);
            m_run[mi] = mnew;

            float sum = 0.f;
            short* prow = Pw + (mi * 16 + c) * PQ_STRIDE + g * 4;
#pragma unroll
            for (int ni = 0; ni < 8; ni++) {
                s4v pk;
#pragma unroll
                for (int r = 0; r < 4; r++) {
                    const float p = __expf(sT[ni][r] - mnew);
                    sum += p;
                    pk[r] = __builtin_bit_cast(short, (bf16)p);
                }
                *(s4v*)(prow + ni * 16) = pk;
            }
            sum += __shfl_xor(sum, 16);
            sum += __shfl_xor(sum, 32);
            l_run[mi] = l_run[mi] * alpha + sum;

#pragma unroll
            for (int di = 0; di < 4; di++)
#pragma unroll
                for (int r = 0; r < 4; r++) o[mi][di][r] *= alpha;
        }

        // O^T += V^T * P  (A = V^T frag from global, B = P from per-wave LDS)
#pragma unroll
        for (int ks2 = 0; ks2 < 4; ks2++) {
            short8 pf[2], vf[4];
#pragma unroll
            for (int mi = 0; mi < 2; mi++)
                pf[mi] = *(const short8*)(Pw + (mi * 16 + c) * PQ_STRIDE + ks2 * 32 + g * 8);
#pragma unroll
            for (int di = 0; di < 4; di++)
                vf[di] = *(const short8*)(Vtg + (size_t)(di * 16 + c) * 2048
                                             + k0 + ks2 * 32 + g * 8);
#pragma unroll
            for (int mi = 0; mi < 2; mi++)
#pragma unroll
                for (int di = 0; di < 4; di++)
                    o[mi][di] = MFMA16(vf[di], pf[mi], o[mi][di]);
        }
        // no barriers anywhere: P is per-wave private, V/K direct from global
    }

    // epilogue: O /= l; lane holds q = mi*16+c, d = di*16+g*4+r
    const int b = bh >> 4, h = bh & 15;
#pragma unroll
    for (int mi = 0; mi < 2; mi++) {
        const float inv = 1.0f / l_run[mi];
        const int srow = q0 + w * 32 + mi * 16 + c;
#pragma unroll
        for (int di = 0; di < 4; di++) {
            s4v pk;
#pragma unroll
            for (int r = 0; r < 4; r++)
                pk[r] = __builtin_bit_cast(short, (bf16)(o[mi][di][r] * inv));
            *(s4v*)(attn_out + ((size_t)(b * 2048 + srow)) * 1024
                             + h * 64 + di * 16 + g * 4) = pk;
        }
    }
}

// ---------------------------------------------------------------------------
// Stage 3: out = attn @ Wo^T + bo -> fp32. grid (8, 64).
// ---------------------------------------------------------------------------
__global__ __launch_bounds__(256) void out_gemm(
    const bf16* __restrict__ A, const float* __restrict__ Wo,
    const float* __restrict__ bo, float* __restrict__ C)
{
    __shared__ __align__(16) short As[128 * 32];
    __shared__ __align__(16) short Bs[128 * BS_STRIDE];

    const int m0 = blockIdx.y * 128;
    const int n0 = blockIdx.x * 128;

    floatx4 acc[4][4];
    gemm128_async(A, Wo, 1024, m0, n0, As, Bs, acc);

    const int lane = threadIdx.x & 63;
    const int w = threadIdx.x >> 6;
    const int wm = w >> 1, wn = w & 1;
    const int g = lane >> 4, c = lane & 15;

#pragma unroll
    for (int ni = 0; ni < 4; ni++) {
        const int n = n0 + wn * 64 + ni * 16 + c;
        const float bb = bo[n];
#pragma unroll
        for (int mi = 0; mi < 4; mi++) {
#pragma unroll
            for (int r = 0; r < 4; r++) {
                const int m = m0 + wm * 64 + mi * 16 + g * 4 + r;
                C[(size_t)m * 1024 + n] = acc[mi][ni][r] + bb;
            }
        }
    }
}

// ---------------------------------------------------------------------------
extern "C" void kernel_launch(void* const* d_in, const int* in_sizes, int n_in,
                              void* d_out, int out_size, void* d_ws, size_t ws_size,
                              hipStream_t stream)
{
    const float* x  = (const float*)d_in[0];
    const float* Wq = (const float*)d_in[1];
    const float* bq = (const float*)d_in[2];
    const float* Wk = (const float*)d_in[3];
    const float* bk = (const float*)d_in[4];
    const float* Wv = (const float*)d_in[5];
    const float* bv = (const float*)d_in[6];
    const float* Wo = (const float*)d_in[7];
    const float* bo = (const float*)d_in[8];
    float* out = (float*)d_out;

    bf16* qkv  = (bf16*)d_ws;                       // 3 x 8192x1024 bf16 = 48 MB
    bf16* xb   = qkv + 3u * 8192u * 1024u;          // 16 MB: Xb (stage 0-1)...
    bf16* attn = xb;                                 // ...then attn-out (stage 2-3)

    cvt_x<<<dim3(8192), dim3(256), 0, stream>>>(x, xb);
    qkv_gemm<<<dim3(8, 64, 3), dim3(256), 0, stream>>>(xb, Wq, Wk, Wv, bq, bk, bv, qkv);
    attn_kernel<<<dim3(16, 64), dim3(256), 0, stream>>>(qkv, attn);
    out_gemm<<<dim3(8, 64), dim3(256), 0, stream>>>(attn, Wo, bo, out);
}

// Round 6
// 506.433 us; speedup vs baseline: 1.4302x; 1.4302x over previous
//
#include <hip/hip_runtime.h>
#include <math.h>

// MultiHeadSelfAttention: B=4, S=2048, E=1024, H=16, Dh=64. fp32 in/out,
// bf16 MFMA internally, fp32 accumulate.
//
// Stage 1: qkv_gemm -> ws (bf16): q (pre-scaled 1/32) [bh][s][d],
//                                 k [bh][s][d], v TRANSPOSED [bh][d][s]
// Stage 2: attn     -> flash attention, S^T = K Q^T per-lane softmax (__expf),
//                      XOR-swizzled LDS (conflict-free b128 reads),
//                      V^T tile LDS-staged per block, P per-wave in LDS.
// Stage 3: out_gemm -> @ Wo^T + bo -> d_out (fp32)

typedef __bf16 bf16;
typedef __attribute__((ext_vector_type(8))) short short8;
typedef __attribute__((ext_vector_type(4))) short s4v;
typedef __attribute__((ext_vector_type(4))) float floatx4;

#define MFMA16(a, b, c) __builtin_amdgcn_mfma_f32_16x16x32_bf16((a), (b), (c), 0, 0, 0)

#define LDS_STRIDE 56   // GEMM tiles: 32 -> 56 shorts (112 B)
// Attention LDS: unpadded stride 128 shorts; bank decorrelation via XOR of the
// 8-short unit index with (row & 15). b64/b128 accesses stay contiguous.
#define SCALE32 0.03125f   // 1/sqrt(1024), folded into q at stage 1 (natural-exp domain)

__device__ __forceinline__ short8 frag8(const bf16* __restrict__ p) {
    return *(const short8*)p;
}
__device__ __forceinline__ short8 frag8(const float* __restrict__ p) {
    const floatx4 a = *(const floatx4*)p;
    const floatx4 b = *(const floatx4*)(p + 4);
    short8 r;
#pragma unroll
    for (int j = 0; j < 4; j++) {
        r[j]     = __builtin_bit_cast(short, (bf16)a[j]);
        r[4 + j] = __builtin_bit_cast(short, (bf16)b[j]);
    }
    return r;
}

// ---------------------------------------------------------------------------
// 128x128-tile GEMM core: C[m][n] = sum_k A[m][k] * B[n][k]
// ---------------------------------------------------------------------------
template <typename TA, typename TB>
__device__ __forceinline__ void gemm128_core(
    const TA* __restrict__ A, const TB* __restrict__ B, int K,
    int m0, int n0, short* As, short* Bs, floatx4 acc[4][4])
{
    const int tid  = threadIdx.x;
    const int lane = tid & 63;
    const int w    = tid >> 6;
    const int wm   = w >> 1, wn = w & 1;
    const int g    = lane >> 4, c = lane & 15;
    const int lrow = tid >> 2;
    const int lc8  = (tid & 3) * 8;

#pragma unroll
    for (int mi = 0; mi < 4; mi++)
#pragma unroll
        for (int ni = 0; ni < 4; ni++)
            acc[mi][ni] = (floatx4){0.f, 0.f, 0.f, 0.f};

    for (int k0 = 0; k0 < K; k0 += 32) {
        *(short8*)(As + lrow * LDS_STRIDE + lc8) =
            frag8(A + (size_t)(m0 + lrow) * K + k0 + lc8);
        *(short8*)(As + (lrow + 64) * LDS_STRIDE + lc8) =
            frag8(A + (size_t)(m0 + lrow + 64) * K + k0 + lc8);
        *(short8*)(Bs + lrow * LDS_STRIDE + lc8) =
            frag8(B + (size_t)(n0 + lrow) * K + k0 + lc8);
        *(short8*)(Bs + (lrow + 64) * LDS_STRIDE + lc8) =
            frag8(B + (size_t)(n0 + lrow + 64) * K + k0 + lc8);
        __syncthreads();

        short8 af[4], bfr[4];
#pragma unroll
        for (int mi = 0; mi < 4; mi++)
            af[mi] = *(const short8*)(As + (wm * 64 + mi * 16 + c) * LDS_STRIDE + g * 8);
#pragma unroll
        for (int ni = 0; ni < 4; ni++)
            bfr[ni] = *(const short8*)(Bs + (wn * 64 + ni * 16 + c) * LDS_STRIDE + g * 8);
#pragma unroll
        for (int mi = 0; mi < 4; mi++)
#pragma unroll
            for (int ni = 0; ni < 4; ni++)
                acc[mi][ni] = MFMA16(af[mi], bfr[ni], acc[mi][ni]);
        __syncthreads();
    }
}

// ---------------------------------------------------------------------------
// Stage 1: q/k/v projections. q scaled 1/32, [bh][s][64]; k [bh][s][64];
//          v TRANSPOSED [bh][64][2048]. grid (8, 64, 3), block 256
// ---------------------------------------------------------------------------
__global__ __launch_bounds__(256) void qkv_gemm(
    const float* __restrict__ X,
    const float* __restrict__ Wq, const float* __restrict__ Wk, const float* __restrict__ Wv,
    const float* __restrict__ bq, const float* __restrict__ bk, const float* __restrict__ bv,
    bf16* __restrict__ qkv)
{
    __shared__ __align__(16) short As[128 * LDS_STRIDE];
    __shared__ __align__(16) short Bs[128 * LDS_STRIDE];

    const int z = blockIdx.z;
    const float* W    = (z == 0) ? Wq : (z == 1) ? Wk : Wv;
    const float* bias = (z == 0) ? bq : (z == 1) ? bk : bv;
    bf16* outz = qkv + (size_t)z * (8192u * 1024u);
    const float oscale = (z == 0) ? SCALE32 : 1.0f;

    const int m0 = blockIdx.y * 128;
    const int n0 = blockIdx.x * 128;

    floatx4 acc[4][4];
    gemm128_core(X, W, 1024, m0, n0, As, Bs, acc);

    const int lane = threadIdx.x & 63;
    const int w = threadIdx.x >> 6;
    const int wm = w >> 1, wn = w & 1;
    const int g = lane >> 4, c = lane & 15;

    if (z < 2) {
#pragma unroll
        for (int ni = 0; ni < 4; ni++) {
            const int n = n0 + wn * 64 + ni * 16 + c;
            const float bb = bias[n];
            const int h = n >> 6, d = n & 63;
#pragma unroll
            for (int mi = 0; mi < 4; mi++) {
#pragma unroll
                for (int r = 0; r < 4; r++) {
                    const int m = m0 + wm * 64 + mi * 16 + g * 4 + r;
                    const int b = m >> 11, s = m & 2047;
                    outz[(((size_t)((b << 4) | h)) * 2048 + s) * 64 + d] =
                        (bf16)((acc[mi][ni][r] + bb) * oscale);
                }
            }
        }
    } else {
        // V transposed: [bh][d][s]; 4 regs = 4 consecutive s -> b64 store
#pragma unroll
        for (int ni = 0; ni < 4; ni++) {
            const int n = n0 + wn * 64 + ni * 16 + c;
            const float bb = bias[n];
            const int h = n >> 6, d = n & 63;
#pragma unroll
            for (int mi = 0; mi < 4; mi++) {
                const int m = m0 + wm * 64 + mi * 16 + g * 4;
                const int b = m >> 11, s = m & 2047;
                s4v pk;
#pragma unroll
                for (int r = 0; r < 4; r++)
                    pk[r] = __builtin_bit_cast(short, (bf16)(acc[mi][ni][r] + bb));
                *(s4v*)(outz + (((size_t)((b << 4) | h)) * 64 + d) * 2048 + s) = pk;
            }
        }
    }
}

// ---------------------------------------------------------------------------
// Stage 2: flash attention. grid (16, 64), block 256 (4 waves).
// S^T = K*Q^T  (C-layout: q = lane&15 -> per-lane softmax, __expf)
// V^T tile LDS-staged per block; P per-wave LDS. XOR-swizzled banks.
// O^T = V^T*P  (C-layout: q = lane&15, d = (lane>>4)*4+reg)
// ---------------------------------------------------------------------------
__global__ __launch_bounds__(256) void attn_kernel(
    const bf16* __restrict__ qkv, bf16* __restrict__ attn_out)
{
    __shared__ __align__(16) short Vts[64 * 128];       // 16 KB, swizzled
    __shared__ __align__(16) short Pq[4 * 32 * 128];    // 32 KB, swizzled

    const int bh = blockIdx.y;            // b = bh>>4, h = bh&15
    const int q0 = blockIdx.x * 128;
    const bf16* Q   = qkv + (size_t)bh * 131072u;                 // [s][64], pre-scaled
    const bf16* Kp  = qkv + 8388608u + (size_t)bh * 131072u;      // [s][64]
    const bf16* Vtg = qkv + 16777216u + (size_t)bh * 131072u;     // [64][2048]

    const int tid  = threadIdx.x;
    const int lane = tid & 63;
    const int w    = tid >> 6;
    const int g    = lane >> 4, c = lane & 15;
    short* Pw = Pq + w * 32 * 128;

    // V^T staging map: per i, 16-lane cluster covers one 256B row segment
    const int vrow = tid >> 4;           // 0..15 (+ i*16)
    const int vunit = tid & 15;          // logical 8-short unit within row

    // Q fragments (B-operand: n = lane&15 = q, k-contiguous), resident
    short8 qf[2][2];
#pragma unroll
    for (int mi = 0; mi < 2; mi++)
#pragma unroll
        for (int ks = 0; ks < 2; ks++)
            qf[mi][ks] = *(const short8*)(Q + (size_t)(q0 + w * 32 + mi * 16 + c) * 64
                                            + ks * 32 + g * 8);

    floatx4 o[2][4];
#pragma unroll
    for (int mi = 0; mi < 2; mi++)
#pragma unroll
        for (int di = 0; di < 4; di++)
            o[mi][di] = (floatx4){0.f, 0.f, 0.f, 0.f};
    float m_run[2] = {-1e30f, -1e30f};
    float l_run[2] = {0.f, 0.f};

    for (int kb = 0; kb < 16; kb++) {
        const int k0 = kb * 128;

        __syncthreads();  // prev iteration's PV reads of Vts complete

        // stage V^T tile (b128 in/out, unit-XOR swizzled destination)
        short8 vst[4];
#pragma unroll
        for (int i = 0; i < 4; i++)
            vst[i] = *(const short8*)(Vtg + (size_t)(vrow + i * 16) * 2048 + k0 + vunit * 8);
#pragma unroll
        for (int i = 0; i < 4; i++)
            *(short8*)(Vts + (vrow + i * 16) * 128 + ((vunit ^ vrow) << 3)) = vst[i];

        // S^T = K * Q^T : 32 queries x 128 keys (kf shared across both mi)
        floatx4 sT[2][8];
#pragma unroll
        for (int mi = 0; mi < 2; mi++)
#pragma unroll
            for (int ni = 0; ni < 8; ni++) sT[mi][ni] = (floatx4){0.f, 0.f, 0.f, 0.f};
#pragma unroll
        for (int ks = 0; ks < 2; ks++) {
            short8 kf[8];
#pragma unroll
            for (int ni = 0; ni < 8; ni++)
                kf[ni] = *(const short8*)(Kp + (size_t)(k0 + ni * 16 + c) * 64
                                             + ks * 32 + g * 8);
#pragma unroll
            for (int mi = 0; mi < 2; mi++)
#pragma unroll
                for (int ni = 0; ni < 8; ni++)
                    sT[mi][ni] = MFMA16(kf[ni], qf[mi][ks], sT[mi][ni]);
        }

        // per-lane online softmax (lane's query = mi*16 + c), natural exp
#pragma unroll
        for (int mi = 0; mi < 2; mi++) {
            float mx = -1e30f;
#pragma unroll
            for (int ni = 0; ni < 8; ni++)
#pragma unroll
                for (int r = 0; r < 4; r++) mx = fmaxf(mx, sT[mi][ni][r]);
            mx = fmaxf(mx, __shfl_xor(mx, 16));
            mx = fmaxf(mx, __shfl_xor(mx, 32));
            const float mnew = fmaxf(m_run[mi], mx);
            const float alpha = __expf(m_run[mi] - mnew);
            m_run[mi] = mnew;

            float sum = 0.f;
            short* prow = Pw + (mi * 16 + c) * 128;
#pragma unroll
            for (int ni = 0; ni < 8; ni++) {
                s4v pk;
#pragma unroll
                for (int r = 0; r < 4; r++) {
                    const float p = __expf(sT[mi][ni][r] - mnew);
                    sum += p;
                    pk[r] = __builtin_bit_cast(short, (bf16)p);
                }
                // logical col = ni*16 + g*4 -> unit = ni*2 + (g>>1), sub = (g&1)*4
                *(s4v*)(prow + (((ni * 2 + (g >> 1)) ^ c) << 3) + (g & 1) * 4) = pk;
            }
            sum += __shfl_xor(sum, 16);
            sum += __shfl_xor(sum, 32);
            l_run[mi] = l_run[mi] * alpha + sum;

#pragma unroll
            for (int di = 0; di < 4; di++)
#pragma unroll
                for (int r = 0; r < 4; r++) o[mi][di][r] *= alpha;
        }

        __syncthreads();  // Vts staged & visible (P is per-wave private)

        // O^T += V^T * P   (A = V^T frag, B = P frag; both swizzle-read)
#pragma unroll
        for (int ks2 = 0; ks2 < 4; ks2++) {
            short8 pf[2], vf[4];
#pragma unroll
            for (int mi = 0; mi < 2; mi++)
                pf[mi] = *(const short8*)(Pw + (mi * 16 + c) * 128
                                             + (((ks2 * 4 + g) ^ c) << 3));
#pragma unroll
            for (int di = 0; di < 4; di++)
                vf[di] = *(const short8*)(Vts + (di * 16 + c) * 128
                                              + (((ks2 * 4 + g) ^ c) << 3));
#pragma unroll
            for (int mi = 0; mi < 2; mi++)
#pragma unroll
                for (int di = 0; di < 4; di++)
                    o[mi][di] = MFMA16(vf[di], pf[mi], o[mi][di]);
        }
    }

    // epilogue: O /= l; lane holds q = mi*16+c, d = di*16+g*4+r
    const int b = bh >> 4, h = bh & 15;
#pragma unroll
    for (int mi = 0; mi < 2; mi++) {
        const float inv = 1.0f / l_run[mi];
        const int srow = q0 + w * 32 + mi * 16 + c;
#pragma unroll
        for (int di = 0; di < 4; di++) {
            s4v pk;
#pragma unroll
            for (int r = 0; r < 4; r++)
                pk[r] = __builtin_bit_cast(short, (bf16)(o[mi][di][r] * inv));
            *(s4v*)(attn_out + ((size_t)(b * 2048 + srow)) * 1024
                             + h * 64 + di * 16 + g * 4) = pk;
        }
    }
}

// ---------------------------------------------------------------------------
// Stage 3: out = attn @ Wo^T + bo -> fp32. grid (8, 64).
// ---------------------------------------------------------------------------
__global__ __launch_bounds__(256) void out_gemm(
    const bf16* __restrict__ A, const float* __restrict__ Wo,
    const float* __restrict__ bo, float* __restrict__ C)
{
    __shared__ __align__(16) short As[128 * LDS_STRIDE];
    __shared__ __align__(16) short Bs[128 * LDS_STRIDE];

    const int m0 = blockIdx.y * 128;
    const int n0 = blockIdx.x * 128;

    floatx4 acc[4][4];
    gemm128_core(A, Wo, 1024, m0, n0, As, Bs, acc);

    const int lane = threadIdx.x & 63;
    const int w = threadIdx.x >> 6;
    const int wm = w >> 1, wn = w & 1;
    const int g = lane >> 4, c = lane & 15;

#pragma unroll
    for (int ni = 0; ni < 4; ni++) {
        const int n = n0 + wn * 64 + ni * 16 + c;
        const float bb = bo[n];
#pragma unroll
        for (int mi = 0; mi < 4; mi++) {
#pragma unroll
            for (int r = 0; r < 4; r++) {
                const int m = m0 + wm * 64 + mi * 16 + g * 4 + r;
                C[(size_t)m * 1024 + n] = acc[mi][ni][r] + bb;
            }
        }
    }
}

// ---------------------------------------------------------------------------
extern "C" void kernel_launch(void* const* d_in, const int* in_sizes, int n_in,
                              void* d_out, int out_size, void* d_ws, size_t ws_size,
                              hipStream_t stream)
{
    const float* x  = (const float*)d_in[0];
    const float* Wq = (const float*)d_in[1];
    const float* bq = (const float*)d_in[2];
    const float* Wk = (const float*)d_in[3];
    const float* bk = (const float*)d_in[4];
    const float* Wv = (const float*)d_in[5];
    const float* bv = (const float*)d_in[6];
    const float* Wo = (const float*)d_in[7];
    const float* bo = (const float*)d_in[8];
    float* out = (float*)d_out;

    bf16* qkv  = (bf16*)d_ws;                       // 3 x 8192x1024 bf16 = 48 MB
    bf16* attn = qkv + 3u * 8192u * 1024u;          // 16 MB

    qkv_gemm<<<dim3(8, 64, 3), dim3(256), 0, stream>>>(x, Wq, Wk, Wv, bq, bk, bv, qkv);
    attn_kernel<<<dim3(16, 64), dim3(256), 0, stream>>>(qkv, attn);
    out_gemm<<<dim3(8, 64), dim3(256), 0, stream>>>(attn, Wo, bo, out);
}

// Round 7
// 479.553 us; speedup vs baseline: 1.5103x; 1.0561x over previous
//
#include <hip/hip_runtime.h>
#include <math.h>

// MultiHeadSelfAttention: B=4, S=2048, E=1024, H=16, Dh=64. fp32 in/out,
// bf16 MFMA internally, fp32 accumulate.
//
// Stage 1: qkv_gemm -> ws (bf16): q (pre-scaled 1/32) [bh][s][d],
//                                 k [bh][s][d], v TRANSPOSED [bh][d][s]
// Stage 2: attn     -> ZERO-BARRIER flash attention: S^T = K Q^T per-lane
//                      softmax (__expf), K/V^T frags direct from global
//                      (L1/L2-shared), P per-wave in XOR-swizzled LDS.
// Stage 3: out_gemm -> @ Wo^T + bo -> d_out (fp32)

typedef __bf16 bf16;
typedef __attribute__((ext_vector_type(8))) short short8;
typedef __attribute__((ext_vector_type(4))) short s4v;
typedef __attribute__((ext_vector_type(4))) float floatx4;

#define MFMA16(a, b, c) __builtin_amdgcn_mfma_f32_16x16x32_bf16((a), (b), (c), 0, 0, 0)

#define LDS_STRIDE 56   // GEMM tiles: 32 -> 56 shorts (112 B)
#define SCALE32 0.03125f   // 1/sqrt(1024), folded into q at stage 1

__device__ __forceinline__ short8 frag8(const bf16* __restrict__ p) {
    return *(const short8*)p;
}
__device__ __forceinline__ short8 frag8(const float* __restrict__ p) {
    const floatx4 a = *(const floatx4*)p;
    const floatx4 b = *(const floatx4*)(p + 4);
    short8 r;
#pragma unroll
    for (int j = 0; j < 4; j++) {
        r[j]     = __builtin_bit_cast(short, (bf16)a[j]);
        r[4 + j] = __builtin_bit_cast(short, (bf16)b[j]);
    }
    return r;
}

// ---------------------------------------------------------------------------
// 128x128-tile GEMM core: C[m][n] = sum_k A[m][k] * B[n][k]
// ---------------------------------------------------------------------------
template <typename TA, typename TB>
__device__ __forceinline__ void gemm128_core(
    const TA* __restrict__ A, const TB* __restrict__ B, int K,
    int m0, int n0, short* As, short* Bs, floatx4 acc[4][4])
{
    const int tid  = threadIdx.x;
    const int lane = tid & 63;
    const int w    = tid >> 6;
    const int wm   = w >> 1, wn = w & 1;
    const int g    = lane >> 4, c = lane & 15;
    const int lrow = tid >> 2;
    const int lc8  = (tid & 3) * 8;

#pragma unroll
    for (int mi = 0; mi < 4; mi++)
#pragma unroll
        for (int ni = 0; ni < 4; ni++)
            acc[mi][ni] = (floatx4){0.f, 0.f, 0.f, 0.f};

    for (int k0 = 0; k0 < K; k0 += 32) {
        *(short8*)(As + lrow * LDS_STRIDE + lc8) =
            frag8(A + (size_t)(m0 + lrow) * K + k0 + lc8);
        *(short8*)(As + (lrow + 64) * LDS_STRIDE + lc8) =
            frag8(A + (size_t)(m0 + lrow + 64) * K + k0 + lc8);
        *(short8*)(Bs + lrow * LDS_STRIDE + lc8) =
            frag8(B + (size_t)(n0 + lrow) * K + k0 + lc8);
        *(short8*)(Bs + (lrow + 64) * LDS_STRIDE + lc8) =
            frag8(B + (size_t)(n0 + lrow + 64) * K + k0 + lc8);
        __syncthreads();

        short8 af[4], bfr[4];
#pragma unroll
        for (int mi = 0; mi < 4; mi++)
            af[mi] = *(const short8*)(As + (wm * 64 + mi * 16 + c) * LDS_STRIDE + g * 8);
#pragma unroll
        for (int ni = 0; ni < 4; ni++)
            bfr[ni] = *(const short8*)(Bs + (wn * 64 + ni * 16 + c) * LDS_STRIDE + g * 8);
#pragma unroll
        for (int mi = 0; mi < 4; mi++)
#pragma unroll
            for (int ni = 0; ni < 4; ni++)
                acc[mi][ni] = MFMA16(af[mi], bfr[ni], acc[mi][ni]);
        __syncthreads();
    }
}

// ---------------------------------------------------------------------------
// Stage 1: q/k/v projections. q scaled 1/32, [bh][s][64]; k [bh][s][64];
//          v TRANSPOSED [bh][64][2048]. grid (8, 64, 3), block 256
// ---------------------------------------------------------------------------
__global__ __launch_bounds__(256) void qkv_gemm(
    const float* __restrict__ X,
    const float* __restrict__ Wq, const float* __restrict__ Wk, const float* __restrict__ Wv,
    const float* __restrict__ bq, const float* __restrict__ bk, const float* __restrict__ bv,
    bf16* __restrict__ qkv)
{
    __shared__ __align__(16) short As[128 * LDS_STRIDE];
    __shared__ __align__(16) short Bs[128 * LDS_STRIDE];

    const int z = blockIdx.z;
    const float* W    = (z == 0) ? Wq : (z == 1) ? Wk : Wv;
    const float* bias = (z == 0) ? bq : (z == 1) ? bk : bv;
    bf16* outz = qkv + (size_t)z * (8192u * 1024u);
    const float oscale = (z == 0) ? SCALE32 : 1.0f;

    const int m0 = blockIdx.y * 128;
    const int n0 = blockIdx.x * 128;

    floatx4 acc[4][4];
    gemm128_core(X, W, 1024, m0, n0, As, Bs, acc);

    const int lane = threadIdx.x & 63;
    const int w = threadIdx.x >> 6;
    const int wm = w >> 1, wn = w & 1;
    const int g = lane >> 4, c = lane & 15;

    if (z < 2) {
#pragma unroll
        for (int ni = 0; ni < 4; ni++) {
            const int n = n0 + wn * 64 + ni * 16 + c;
            const float bb = bias[n];
            const int h = n >> 6, d = n & 63;
#pragma unroll
            for (int mi = 0; mi < 4; mi++) {
#pragma unroll
                for (int r = 0; r < 4; r++) {
                    const int m = m0 + wm * 64 + mi * 16 + g * 4 + r;
                    const int b = m >> 11, s = m & 2047;
                    outz[(((size_t)((b << 4) | h)) * 2048 + s) * 64 + d] =
                        (bf16)((acc[mi][ni][r] + bb) * oscale);
                }
            }
        }
    } else {
        // V transposed: [bh][d][s]; 4 regs = 4 consecutive s -> b64 store
#pragma unroll
        for (int ni = 0; ni < 4; ni++) {
            const int n = n0 + wn * 64 + ni * 16 + c;
            const float bb = bias[n];
            const int h = n >> 6, d = n & 63;
#pragma unroll
            for (int mi = 0; mi < 4; mi++) {
                const int m = m0 + wm * 64 + mi * 16 + g * 4;
                const int b = m >> 11, s = m & 2047;
                s4v pk;
#pragma unroll
                for (int r = 0; r < 4; r++)
                    pk[r] = __builtin_bit_cast(short, (bf16)(acc[mi][ni][r] + bb));
                *(s4v*)(outz + (((size_t)((b << 4) | h)) * 64 + d) * 2048 + s) = pk;
            }
        }
    }
}

// ---------------------------------------------------------------------------
// Stage 2: ZERO-BARRIER flash attention. grid (16, 64), block 256 (4 waves).
// S^T = K*Q^T  (C-layout: q = lane&15 -> per-lane softmax, __expf)
// K and V^T fragments direct from global (wave-uniform -> L1/L2 shared).
// P per-wave in XOR-swizzled LDS (32 KB total). No __syncthreads anywhere.
// O^T = V^T*P  (C-layout: q = lane&15, d = (lane>>4)*4+reg)
// ---------------------------------------------------------------------------
__global__ __launch_bounds__(256) void attn_kernel(
    const bf16* __restrict__ qkv, bf16* __restrict__ attn_out)
{
    __shared__ __align__(16) short Pq[4 * 32 * 128];    // 32 KB, swizzled

    const int bh = blockIdx.y;            // b = bh>>4, h = bh&15
    const int q0 = blockIdx.x * 128;
    const bf16* Q   = qkv + (size_t)bh * 131072u;                 // [s][64], pre-scaled
    const bf16* Kp  = qkv + 8388608u + (size_t)bh * 131072u;      // [s][64]
    const bf16* Vtg = qkv + 16777216u + (size_t)bh * 131072u;     // [64][2048]

    const int tid  = threadIdx.x;
    const int lane = tid & 63;
    const int w    = tid >> 6;
    const int g    = lane >> 4, c = lane & 15;
    short* Pw = Pq + w * 32 * 128;

    // Q fragments (B-operand: n = lane&15 = q, k-contiguous), resident
    short8 qf[2][2];
#pragma unroll
    for (int mi = 0; mi < 2; mi++)
#pragma unroll
        for (int ks = 0; ks < 2; ks++)
            qf[mi][ks] = *(const short8*)(Q + (size_t)(q0 + w * 32 + mi * 16 + c) * 64
                                            + ks * 32 + g * 8);

    floatx4 o[2][4];
#pragma unroll
    for (int mi = 0; mi < 2; mi++)
#pragma unroll
        for (int di = 0; di < 4; di++)
            o[mi][di] = (floatx4){0.f, 0.f, 0.f, 0.f};
    float m_run[2] = {-1e30f, -1e30f};
    float l_run[2] = {0.f, 0.f};

    for (int kb = 0; kb < 16; kb++) {
        const int k0 = kb * 128;

        // S^T = K * Q^T : 32 queries x 128 keys (kf shared across both mi)
        floatx4 sT[2][8];
#pragma unroll
        for (int mi = 0; mi < 2; mi++)
#pragma unroll
            for (int ni = 0; ni < 8; ni++) sT[mi][ni] = (floatx4){0.f, 0.f, 0.f, 0.f};
#pragma unroll
        for (int ks = 0; ks < 2; ks++) {
            short8 kf[8];
#pragma unroll
            for (int ni = 0; ni < 8; ni++)
                kf[ni] = *(const short8*)(Kp + (size_t)(k0 + ni * 16 + c) * 64
                                             + ks * 32 + g * 8);
#pragma unroll
            for (int mi = 0; mi < 2; mi++)
#pragma unroll
                for (int ni = 0; ni < 8; ni++)
                    sT[mi][ni] = MFMA16(kf[ni], qf[mi][ks], sT[mi][ni]);
        }

        // per-lane online softmax (lane's query = mi*16 + c), natural exp
#pragma unroll
        for (int mi = 0; mi < 2; mi++) {
            float mx = -1e30f;
#pragma unroll
            for (int ni = 0; ni < 8; ni++)
#pragma unroll
                for (int r = 0; r < 4; r++) mx = fmaxf(mx, sT[mi][ni][r]);
            mx = fmaxf(mx, __shfl_xor(mx, 16));
            mx = fmaxf(mx, __shfl_xor(mx, 32));
            const float mnew = fmaxf(m_run[mi], mx);
            const float alpha = __expf(m_run[mi] - mnew);
            m_run[mi] = mnew;

            float sum = 0.f;
            short* prow = Pw + (mi * 16 + c) * 128;
#pragma unroll
            for (int ni = 0; ni < 8; ni++) {
                s4v pk;
#pragma unroll
                for (int r = 0; r < 4; r++) {
                    const float p = __expf(sT[mi][ni][r] - mnew);
                    sum += p;
                    pk[r] = __builtin_bit_cast(short, (bf16)p);
                }
                // logical col = ni*16 + g*4 -> unit = ni*2 + (g>>1), sub = (g&1)*4
                *(s4v*)(prow + (((ni * 2 + (g >> 1)) ^ c) << 3) + (g & 1) * 4) = pk;
            }
            sum += __shfl_xor(sum, 16);
            sum += __shfl_xor(sum, 32);
            l_run[mi] = l_run[mi] * alpha + sum;

#pragma unroll
            for (int di = 0; di < 4; di++)
#pragma unroll
                for (int r = 0; r < 4; r++) o[mi][di][r] *= alpha;
        }

        // O^T += V^T * P  (A = V^T frag direct from global; B = P swizzle-read)
#pragma unroll
        for (int ks2 = 0; ks2 < 4; ks2++) {
            short8 pf[2], vf[4];
#pragma unroll
            for (int mi = 0; mi < 2; mi++)
                pf[mi] = *(const short8*)(Pw + (mi * 16 + c) * 128
                                             + (((ks2 * 4 + g) ^ c) << 3));
#pragma unroll
            for (int di = 0; di < 4; di++)
                vf[di] = *(const short8*)(Vtg + (size_t)(di * 16 + c) * 2048
                                              + k0 + ks2 * 32 + g * 8);
#pragma unroll
            for (int mi = 0; mi < 2; mi++)
#pragma unroll
                for (int di = 0; di < 4; di++)
                    o[mi][di] = MFMA16(vf[di], pf[mi], o[mi][di]);
        }
        // no barriers: P is per-wave private (same-wave lgkmcnt ordering),
        // K/V^T served by L1/L2 (wave-uniform addresses, blocks share bh)
    }

    // epilogue: O /= l; lane holds q = mi*16+c, d = di*16+g*4+r
    const int b = bh >> 4, h = bh & 15;
#pragma unroll
    for (int mi = 0; mi < 2; mi++) {
        const float inv = 1.0f / l_run[mi];
        const int srow = q0 + w * 32 + mi * 16 + c;
#pragma unroll
        for (int di = 0; di < 4; di++) {
            s4v pk;
#pragma unroll
            for (int r = 0; r < 4; r++)
                pk[r] = __builtin_bit_cast(short, (bf16)(o[mi][di][r] * inv));
            *(s4v*)(attn_out + ((size_t)(b * 2048 + srow)) * 1024
                             + h * 64 + di * 16 + g * 4) = pk;
        }
    }
}

// ---------------------------------------------------------------------------
// Stage 3: out = attn @ Wo^T + bo -> fp32. grid (8, 64).
// ---------------------------------------------------------------------------
__global__ __launch_bounds__(256) void out_gemm(
    const bf16* __restrict__ A, const float* __restrict__ Wo,
    const float* __restrict__ bo, float* __restrict__ C)
{
    __shared__ __align__(16) short As[128 * LDS_STRIDE];
    __shared__ __align__(16) short Bs[128 * LDS_STRIDE];

    const int m0 = blockIdx.y * 128;
    const int n0 = blockIdx.x * 128;

    floatx4 acc[4][4];
    gemm128_core(A, Wo, 1024, m0, n0, As, Bs, acc);

    const int lane = threadIdx.x & 63;
    const int w = threadIdx.x >> 6;
    const int wm = w >> 1, wn = w & 1;
    const int g = lane >> 4, c = lane & 15;

#pragma unroll
    for (int ni = 0; ni < 4; ni++) {
        const int n = n0 + wn * 64 + ni * 16 + c;
        const float bb = bo[n];
#pragma unroll
        for (int mi = 0; mi < 4; mi++) {
#pragma unroll
            for (int r = 0; r < 4; r++) {
                const int m = m0 + wm * 64 + mi * 16 + g * 4 + r;
                C[(size_t)m * 1024 + n] = acc[mi][ni][r] + bb;
            }
        }
    }
}

// ---------------------------------------------------------------------------
extern "C" void kernel_launch(void* const* d_in, const int* in_sizes, int n_in,
                              void* d_out, int out_size, void* d_ws, size_t ws_size,
                              hipStream_t stream)
{
    const float* x  = (const float*)d_in[0];
    const float* Wq = (const float*)d_in[1];
    const float* bq = (const float*)d_in[2];
    const float* Wk = (const float*)d_in[3];
    const float* bk = (const float*)d_in[4];
    const float* Wv = (const float*)d_in[5];
    const float* bv = (const float*)d_in[6];
    const float* Wo = (const float*)d_in[7];
    const float* bo = (const float*)d_in[8];
    float* out = (float*)d_out;

    bf16* qkv  = (bf16*)d_ws;                       // 3 x 8192x1024 bf16 = 48 MB
    bf16* attn = qkv + 3u * 8192u * 1024u;          // 16 MB

    qkv_gemm<<<dim3(8, 64, 3), dim3(256), 0, stream>>>(x, Wq, Wk, Wv, bq, bk, bv, qkv);
    attn_kernel<<<dim3(16, 64), dim3(256), 0, stream>>>(qkv, attn);
    out_gemm<<<dim3(8, 64), dim3(256), 0, stream>>>(attn, Wo, bo, out);
}